// Round 1
// baseline (134.011 us; speedup 1.0000x reference)
//
#include <hip/hip_runtime.h>
#include <hip/hip_bf16.h>

// Problem constants (from reference)
constexpr int kB   = 16384;   // batch
constexpr int kNeg = 10;      // negatives per example
constexpr int kE   = 128;     // embedding dim
constexpr int kWavesPerBlock = 4;          // 256 threads
constexpr int kPairsPerWave  = 2;          // each wave loops over 2 pairs (4 examples)
constexpr int kBlocks = kB / (2 * kWavesPerBlock * kPairsPerWave);  // 1024

__device__ __forceinline__ float log_sigmoid(float x) {
    // numerically stable: min(x,0) - log1p(exp(-|x|))
    return fminf(x, 0.0f) - log1pf(expf(-fabsf(x)));
}

__global__ __launch_bounds__(256) void w2v_loss_kernel(
    const int*   __restrict__ input_word,
    const int*   __restrict__ context_word,
    const int*   __restrict__ noise_words,
    const float* __restrict__ W_in,
    const float* __restrict__ W_ctx,
    float*       __restrict__ partials)
{
    const int lane = threadIdx.x & 63;
    const int wave = threadIdx.x >> 6;
    const int half = lane >> 5;     // 0 or 1: which example of the pair
    const int l32  = lane & 31;     // lane within half; l32*4 covers E=128

    const int wave_global = blockIdx.x * kWavesPerBlock + wave;
    const int pair0 = wave_global * kPairsPerWave;

    float acc = 0.0f;   // per-lane loss accumulator (only l32==0 lanes contribute)

    for (int p = 0; p < kPairsPerWave; ++p) {
        const int b = (pair0 + p) * 2 + half;
        if (b < kB) {
            const int iw = input_word[b];
            const int cw = context_word[b];
            const float4* __restrict__ crow = (const float4*)(W_in  + (size_t)iw * kE);
            const float4* __restrict__ xrow = (const float4*)(W_ctx + (size_t)cw * kE);
            const float4 c = crow[l32];
            const float4 x = xrow[l32];
            float pos = c.x * x.x + c.y * x.y + c.z * x.z + c.w * x.w;

            float negp[kNeg];
            #pragma unroll
            for (int k = 0; k < kNeg; ++k) {
                const int nw = noise_words[b * kNeg + k];
                const float4* __restrict__ nrow = (const float4*)(W_ctx + (size_t)nw * kE);
                const float4 nv = nrow[l32];
                negp[k] = c.x * nv.x + c.y * nv.y + c.z * nv.z + c.w * nv.w;
            }

            // butterfly reduce within each 32-lane half (xor<32 stays in half)
            #pragma unroll
            for (int off = 16; off > 0; off >>= 1) {
                pos += __shfl_xor(pos, off);
                #pragma unroll
                for (int k = 0; k < kNeg; ++k)
                    negp[k] += __shfl_xor(negp[k], off);
            }

            if (l32 == 0) {
                float s = log_sigmoid(pos);
                #pragma unroll
                for (int k = 0; k < kNeg; ++k)
                    s += log_sigmoid(-negp[k]);   // neg_score = -dot
                acc += s;
            }
        }
    }

    // full 64-lane reduce: sums lane0 (example 2p) + lane32 (example 2p+1)
    #pragma unroll
    for (int off = 32; off > 0; off >>= 1)
        acc += __shfl_xor(acc, off);

    __shared__ float smem[kWavesPerBlock];
    if (lane == 0) smem[wave] = acc;
    __syncthreads();
    if (threadIdx.x == 0) {
        float t = 0.0f;
        #pragma unroll
        for (int w = 0; w < kWavesPerBlock; ++w) t += smem[w];
        partials[blockIdx.x] = t;
    }
}

__global__ __launch_bounds__(256) void w2v_reduce_kernel(
    const float* __restrict__ partials,
    float*       __restrict__ out)
{
    float acc = 0.0f;
    for (int i = threadIdx.x; i < kBlocks; i += 256)
        acc += partials[i];

    #pragma unroll
    for (int off = 32; off > 0; off >>= 1)
        acc += __shfl_xor(acc, off);

    __shared__ float smem[4];
    const int lane = threadIdx.x & 63;
    const int wave = threadIdx.x >> 6;
    if (lane == 0) smem[wave] = acc;
    __syncthreads();
    if (threadIdx.x == 0) {
        const float total = smem[0] + smem[1] + smem[2] + smem[3];
        out[0] = -total / (float)kB;
    }
}

extern "C" void kernel_launch(void* const* d_in, const int* in_sizes, int n_in,
                              void* d_out, int out_size, void* d_ws, size_t ws_size,
                              hipStream_t stream) {
    const int*   input_word   = (const int*)d_in[0];
    const int*   context_word = (const int*)d_in[1];
    const int*   noise_words  = (const int*)d_in[2];
    const float* W_in         = (const float*)d_in[3];
    const float* W_ctx        = (const float*)d_in[4];
    float*       out          = (float*)d_out;
    float*       partials     = (float*)d_ws;   // kBlocks floats (4 KiB)

    w2v_loss_kernel<<<kBlocks, 256, 0, stream>>>(
        input_word, context_word, noise_words, W_in, W_ctx, partials);
    w2v_reduce_kernel<<<1, 256, 0, stream>>>(partials, out);
}

// Round 2
// 125.337 us; speedup vs baseline: 1.0692x; 1.0692x over previous
//
#include <hip/hip_runtime.h>
#include <hip/hip_bf16.h>

// Problem constants (from reference)
constexpr int kB   = 16384;   // batch
constexpr int kNeg = 10;      // negatives per example
constexpr int kE   = 128;     // embedding dim
constexpr int kWavesPerBlock = 4;                 // 256 threads
constexpr int kExPerWave     = 4;                 // 16 lanes per example
constexpr int kBlocks = kB / (kWavesPerBlock * kExPerWave);   // 1024

__device__ __forceinline__ float log_sigmoid(float x) {
    // numerically stable: min(x,0) - log1p(exp(-|x|))
    return fminf(x, 0.0f) - log1pf(expf(-fabsf(x)));
}

__device__ __forceinline__ float dot4(float4 a, float4 b) {
    return a.x * b.x + a.y * b.y + a.z * b.z + a.w * b.w;
}

__global__ __launch_bounds__(256, 4) void w2v_loss_kernel(
    const int*   __restrict__ input_word,
    const int*   __restrict__ context_word,
    const int*   __restrict__ noise_words,
    const float* __restrict__ W_in,
    const float* __restrict__ W_ctx,
    float*       __restrict__ partials)
{
    const int lane = threadIdx.x & 63;
    const int wave = threadIdx.x >> 6;
    const int l16  = lane & 15;               // lane within 16-lane example group
    const int slot = lane >> 4;               // 0..3: which example of the wave

    const int wave_global = blockIdx.x * kWavesPerBlock + wave;
    const int b = wave_global * kExPerWave + slot;   // B=16384 = kBlocks*16 exactly

    // Each 16-lane group covers one E=128 row as 32 float4s: indices l16, l16+16.
    const int iw = input_word[b];
    const int cw = context_word[b];
    const float4* __restrict__ crow = (const float4*)(W_in  + (size_t)iw * kE);
    const float4* __restrict__ xrow = (const float4*)(W_ctx + (size_t)cw * kE);
    const float4 c0 = crow[l16];
    const float4 c1 = crow[l16 + 16];
    const float4 x0 = xrow[l16];
    const float4 x1 = xrow[l16 + 16];
    float pos = dot4(c0, x0) + dot4(c1, x1);

    float negp[kNeg];
    #pragma unroll
    for (int k = 0; k < kNeg; ++k) {
        const int nw = noise_words[b * kNeg + k];
        const float4* __restrict__ nrow = (const float4*)(W_ctx + (size_t)nw * kE);
        const float4 n0 = nrow[l16];
        const float4 n1 = nrow[l16 + 16];
        negp[k] = dot4(c0, n0) + dot4(c1, n1);
    }

    // 4-step butterfly within each 16-lane group (xor masks < 16 stay in-group).
    #pragma unroll
    for (int off = 8; off > 0; off >>= 1) {
        pos += __shfl_xor(pos, off);
        #pragma unroll
        for (int k = 0; k < kNeg; ++k)
            negp[k] += __shfl_xor(negp[k], off);
    }
    // Now every lane in the group holds all 11 full dot products.

    // Distribute the 11 log_sigmoid evaluations across lanes 0..10 of the group.
    float v = pos;                         // lane 0: positive score
    #pragma unroll
    for (int k = 0; k < kNeg; ++k)
        v = (l16 == k + 1) ? -negp[k] : v; // lanes 1..10: negated neg scores
    float s = (l16 < 1 + kNeg) ? log_sigmoid(v) : 0.0f;

    // Sum the 11 terms within the group (4 steps), then across the 4 slots (2 steps).
    #pragma unroll
    for (int off = 8; off > 0; off >>= 1)
        s += __shfl_xor(s, off);
    s += __shfl_xor(s, 16);
    s += __shfl_xor(s, 32);

    __shared__ float smem[kWavesPerBlock];
    if (lane == 0) smem[wave] = s;
    __syncthreads();
    if (threadIdx.x == 0)
        partials[blockIdx.x] = smem[0] + smem[1] + smem[2] + smem[3];
}

__global__ __launch_bounds__(256) void w2v_reduce_kernel(
    const float* __restrict__ partials,
    float*       __restrict__ out)
{
    float acc = 0.0f;
    for (int i = threadIdx.x; i < kBlocks; i += 256)
        acc += partials[i];

    #pragma unroll
    for (int off = 32; off > 0; off >>= 1)
        acc += __shfl_xor(acc, off);

    __shared__ float smem[4];
    const int lane = threadIdx.x & 63;
    const int wave = threadIdx.x >> 6;
    if (lane == 0) smem[wave] = acc;
    __syncthreads();
    if (threadIdx.x == 0) {
        const float total = smem[0] + smem[1] + smem[2] + smem[3];
        out[0] = -total / (float)kB;
    }
}

extern "C" void kernel_launch(void* const* d_in, const int* in_sizes, int n_in,
                              void* d_out, int out_size, void* d_ws, size_t ws_size,
                              hipStream_t stream) {
    const int*   input_word   = (const int*)d_in[0];
    const int*   context_word = (const int*)d_in[1];
    const int*   noise_words  = (const int*)d_in[2];
    const float* W_in         = (const float*)d_in[3];
    const float* W_ctx        = (const float*)d_in[4];
    float*       out          = (float*)d_out;
    float*       partials     = (float*)d_ws;   // kBlocks floats (4 KiB)

    w2v_loss_kernel<<<kBlocks, 256, 0, stream>>>(
        input_word, context_word, noise_words, W_in, W_ctx, partials);
    w2v_reduce_kernel<<<1, 256, 0, stream>>>(partials, out);
}

// Round 3
// 124.697 us; speedup vs baseline: 1.0747x; 1.0051x over previous
//
#include <hip/hip_runtime.h>
#include <hip/hip_bf16.h>

// Problem constants (from reference)
constexpr int kB   = 16384;   // batch
constexpr int kNeg = 10;      // negatives per example
constexpr int kE   = 128;     // embedding dim
constexpr int kWavesPerBlock = 4;                 // 256 threads
constexpr int kExPerWave     = 2;                 // 32 lanes per example
constexpr int kBlocks = kB / (kWavesPerBlock * kExPerWave);   // 2048

__device__ __forceinline__ float log_sigmoid(float x) {
    // numerically stable: min(x,0) - log1p(exp(-|x|))
    return fminf(x, 0.0f) - log1pf(expf(-fabsf(x)));
}

__device__ __forceinline__ float dot4(float4 a, float4 b) {
    return a.x * b.x + a.y * b.y + a.z * b.z + a.w * b.w;
}

// 32 lanes per example: one float4 per lane covers the E=128 row exactly.
// All 12 row gathers per lane are independent -> max memory-level parallelism.
__global__ __launch_bounds__(256, 4) void w2v_loss_kernel(
    const int*   __restrict__ input_word,
    const int*   __restrict__ context_word,
    const int*   __restrict__ noise_words,
    const float* __restrict__ W_in,
    const float* __restrict__ W_ctx,
    float*       __restrict__ partials)
{
    const int lane = threadIdx.x & 63;
    const int wave = threadIdx.x >> 6;
    const int half = lane >> 5;               // which example of the wave
    const int l32  = lane & 31;               // lane within 32-lane group

    const int b = (blockIdx.x * kWavesPerBlock + wave) * kExPerWave + half;

    // Load all indices first (independent scalar loads).
    const int iw = input_word[b];
    const int cw = context_word[b];
    int nw[kNeg];
    #pragma unroll
    for (int k = 0; k < kNeg; ++k)
        nw[k] = noise_words[b * kNeg + k];

    // Issue all 12 row gathers back-to-back (each 1 float4/lane, coalesced 512B/row).
    const float4 c = ((const float4*)(W_in  + (size_t)iw * kE))[l32];
    const float4 x = ((const float4*)(W_ctx + (size_t)cw * kE))[l32];
    float4 nv[kNeg];
    #pragma unroll
    for (int k = 0; k < kNeg; ++k)
        nv[k] = ((const float4*)(W_ctx + (size_t)nw[k] * kE))[l32];

    float pos = dot4(c, x);
    float negp[kNeg];
    #pragma unroll
    for (int k = 0; k < kNeg; ++k)
        negp[k] = dot4(c, nv[k]);

    // 5-step butterfly within each 32-lane half (xor masks < 32 stay in-half).
    #pragma unroll
    for (int off = 16; off > 0; off >>= 1) {
        pos += __shfl_xor(pos, off);
        #pragma unroll
        for (int k = 0; k < kNeg; ++k)
            negp[k] += __shfl_xor(negp[k], off);
    }
    // Every lane now holds all 11 full dot products for its example.

    // Distribute the 11 log_sigmoid evaluations across lanes 0..10 of the half.
    float v = pos;                          // lane 0: positive score
    #pragma unroll
    for (int k = 0; k < kNeg; ++k)
        v = (l32 == k + 1) ? -negp[k] : v;  // lanes 1..10: negated neg scores
    float s = (l32 < 1 + kNeg) ? log_sigmoid(v) : 0.0f;

    // Sum the 11 terms within the half (5 steps), then across halves (1 step).
    #pragma unroll
    for (int off = 16; off > 0; off >>= 1)
        s += __shfl_xor(s, off);
    s += __shfl_xor(s, 32);

    __shared__ float smem[kWavesPerBlock];
    if (lane == 0) smem[wave] = s;
    __syncthreads();
    if (threadIdx.x == 0)
        partials[blockIdx.x] = smem[0] + smem[1] + smem[2] + smem[3];
}

__global__ __launch_bounds__(256) void w2v_reduce_kernel(
    const float* __restrict__ partials,
    float*       __restrict__ out)
{
    float acc = 0.0f;
    for (int i = threadIdx.x; i < kBlocks; i += 256)
        acc += partials[i];

    #pragma unroll
    for (int off = 32; off > 0; off >>= 1)
        acc += __shfl_xor(acc, off);

    __shared__ float smem[4];
    const int lane = threadIdx.x & 63;
    const int wave = threadIdx.x >> 6;
    if (lane == 0) smem[wave] = acc;
    __syncthreads();
    if (threadIdx.x == 0) {
        const float total = smem[0] + smem[1] + smem[2] + smem[3];
        out[0] = -total / (float)kB;
    }
}

extern "C" void kernel_launch(void* const* d_in, const int* in_sizes, int n_in,
                              void* d_out, int out_size, void* d_ws, size_t ws_size,
                              hipStream_t stream) {
    const int*   input_word   = (const int*)d_in[0];
    const int*   context_word = (const int*)d_in[1];
    const int*   noise_words  = (const int*)d_in[2];
    const float* W_in         = (const float*)d_in[3];
    const float* W_ctx        = (const float*)d_in[4];
    float*       out          = (float*)d_out;
    float*       partials     = (float*)d_ws;   // kBlocks floats (8 KiB)

    w2v_loss_kernel<<<kBlocks, 256, 0, stream>>>(
        input_word, context_word, noise_words, W_in, W_ctx, partials);
    w2v_reduce_kernel<<<1, 256, 0, stream>>>(partials, out);
}